// Round 6
// baseline (393.554 us; speedup 1.0000x reference)
//
#include <hip/hip_runtime.h>
#include <math.h>

#define EPS_ 1e-10f
#define MARGIN 2e-3f

__device__ __forceinline__ bool betterd(double v, int i, double w, int j) {
    return (v > w) || (v == w && i < j);
}

// ---------------------------------------------------------------------------
// GEMM: block = 256 thr (4 waves) = 64 rows x 64 experts, one K-slice.
// lane = row; wave w owns experts [16w, 16w+16): acc[16] per thread.
// x staged once per block into LDS transposed (conflict-free b32 reads,
// shared by all 4 waves); W read as wave-uniform s_load quads (L2/K$-hot).
// Grid = ksplit * (N/64) blocks -> 8 blocks/CU, 32 waves/CU.
// zpart[ks][e][row] (lane-coalesced stores).
// ---------------------------------------------------------------------------
template<int KW>
__global__ __launch_bounds__(256, 8)
void gemm_rows(const float* __restrict__ x, const float* __restrict__ W,
               int dim, int N, int ks_count, int rgs,
               float* __restrict__ zpart)
{
    __shared__ float xT[KW][65];   // [k][row]; 65 -> bank (k+row)%32

    const int tid  = threadIdx.x;
    const int lane = tid & 63;           // row within group
    const int e0   = (tid >> 6) * 16;    // wave's expert base
    const int ks = blockIdx.x / rgs;     // consecutive blocks share ks
    const int rg = blockIdx.x % rgs;
    const int r0 = rg * 64;
    const int kslice = dim / ks_count;
    const int k0 = ks * kslice;

    // staging lanes: thread covers 8 floats of one row
    const int srow = tid >> 2;           // 0..63
    const int sk8  = (tid & 3) * 8;      // 0,8,16,24

    float acc[16];
#pragma unroll
    for (int e = 0; e < 16; ++e) acc[e] = 0.0f;

    const float* xsrc = x + (size_t)(r0 + srow) * dim + k0 + sk8;

    for (int w = 0; w < kslice; w += KW) {
        // stage x[64][KW] transposed into LDS (two float4 per thread)
        const float4 va = *(const float4*)(xsrc + w);
        const float4 vb = *(const float4*)(xsrc + w + 4);
        xT[sk8 + 0][srow] = va.x; xT[sk8 + 1][srow] = va.y;
        xT[sk8 + 2][srow] = va.z; xT[sk8 + 3][srow] = va.w;
        xT[sk8 + 4][srow] = vb.x; xT[sk8 + 5][srow] = vb.y;
        xT[sk8 + 6][srow] = vb.z; xT[sk8 + 7][srow] = vb.w;
        __syncthreads();

        const float* wp = W + ((size_t)(k0 + w)) * 64 + e0;
#pragma unroll 2
        for (int k = 0; k < KW; ++k) {
            const float xv = xT[k][lane];
            const float4* __restrict__ wq = (const float4*)(wp + (size_t)k * 64);
            const float4 w0 = wq[0];
            const float4 w1 = wq[1];
            const float4 w2 = wq[2];
            const float4 w3 = wq[3];
            acc[ 0] = fmaf(xv, w0.x, acc[ 0]);
            acc[ 1] = fmaf(xv, w0.y, acc[ 1]);
            acc[ 2] = fmaf(xv, w0.z, acc[ 2]);
            acc[ 3] = fmaf(xv, w0.w, acc[ 3]);
            acc[ 4] = fmaf(xv, w1.x, acc[ 4]);
            acc[ 5] = fmaf(xv, w1.y, acc[ 5]);
            acc[ 6] = fmaf(xv, w1.z, acc[ 6]);
            acc[ 7] = fmaf(xv, w1.w, acc[ 7]);
            acc[ 8] = fmaf(xv, w2.x, acc[ 8]);
            acc[ 9] = fmaf(xv, w2.y, acc[ 9]);
            acc[10] = fmaf(xv, w2.z, acc[10]);
            acc[11] = fmaf(xv, w2.w, acc[11]);
            acc[12] = fmaf(xv, w3.x, acc[12]);
            acc[13] = fmaf(xv, w3.y, acc[13]);
            acc[14] = fmaf(xv, w3.z, acc[14]);
            acc[15] = fmaf(xv, w3.w, acc[15]);
        }
        __syncthreads();
    }

    float* zp = zpart + ((size_t)ks * 64 + e0) * N + r0 + lane;
#pragma unroll
    for (int e = 0; e < 16; ++e)
        zp[(size_t)e * N] = acc[e];
}

// ---------------------------------------------------------------------------
// Epilogue: thread = row. Sum K-split partials (fixed order), + bias,
// in-thread top-2 (strict > => lowest index on ties), 3rd-max gap flag,
// softmax, rz row value. No cross-lane ops.
// ---------------------------------------------------------------------------
__global__ __launch_bounds__(256)
void epilogue(const float* __restrict__ zpart, const float* __restrict__ b,
              int N, int ks_count,
              float* __restrict__ ts, int* __restrict__ sel,
              float* __restrict__ rzrow,
              int* __restrict__ nflags, int* __restrict__ flaglist)
{
    const int row = blockIdx.x * 256 + threadIdx.x;
    if (row >= N) return;

    float acc[64];
#pragma unroll
    for (int e = 0; e < 64; ++e) acc[e] = b[e];
    for (int ks = 0; ks < ks_count; ++ks) {
        const float* zp = zpart + ((size_t)ks * 64) * N + row;
#pragma unroll
        for (int e = 0; e < 64; ++e) acc[e] += zp[(size_t)e * N];
    }

    float v1 = -3.4e38f, v2 = -3.4e38f;
    int i1 = 0, i2 = 0;
#pragma unroll
    for (int e = 0; e < 64; ++e) {
        const float v = acc[e];
        if (v > v1)      { v2 = v1; i2 = i1; v1 = v; i1 = e; }
        else if (v > v2) { v2 = v;  i2 = e; }
    }
    float m3 = -3.4e38f;
#pragma unroll
    for (int e = 0; e < 64; ++e) {
        const float v = acc[e];
        const bool skip = (e == i1) || (e == i2);
        m3 = skip ? m3 : fmaxf(m3, v);
    }

    float ssum = 0.0f;
#pragma unroll
    for (int e = 0; e < 64; ++e) { acc[e] = expf(acc[e] - v1); ssum += acc[e]; }
    const float inv = 1.0f / ssum;
    float srz = 0.0f;
#pragma unroll
    for (int e = 0; e < 64; ++e) {
        float sc = fminf(fmaxf(acc[e] * inv, EPS_), 1.0f - EPS_);
        srz += sc / (1.0f - sc);
    }

    const float s1 = fminf(fmaxf(inv, EPS_), 1.0f - EPS_);
    const float s2 = fminf(fmaxf(expf(v2 - v1) * inv, EPS_), 1.0f - EPS_);
    ts[row * 2 + 0] = s1;
    ts[row * 2 + 1] = s2;
    sel[row * 2 + 0] = i1;
    sel[row * 2 + 1] = i2;
    rzrow[row] = srz;
    if ((v1 - v2) < MARGIN || (v2 - m3) < MARGIN) {
        const int slot = atomicAdd(nflags, 1);
        flaglist[slot] = row;
    }
}

// ---------------------------------------------------------------------------
// fp64 recompute of flagged near-tie rows (4 independent accumulator chains).
// ---------------------------------------------------------------------------
__global__ __launch_bounds__(256)
void fixup(const float* __restrict__ x, const float* __restrict__ W,
           const float* __restrict__ b, int dim,
           const int* __restrict__ nflags, const int* __restrict__ flaglist,
           float* __restrict__ ts, int* __restrict__ sel)
{
    __shared__ double red[256];
    const int tid = threadIdx.x;
    const int e = tid & 63;
    const int q = tid >> 6;
    const int nf = *nflags;
    const int quarter = dim >> 2;

    for (int f = blockIdx.x; f < nf; f += gridDim.x) {
        const int row = flaglist[f];
        const float* xr = x + (size_t)row * dim;
        const int k0 = q * quarter;
        double a0 = 0.0, a1 = 0.0, a2 = 0.0, a3 = 0.0;
        for (int k = k0; k < k0 + quarter; k += 4) {
            a0 = fma((double)xr[k + 0], (double)W[(size_t)(k + 0) * 64 + e], a0);
            a1 = fma((double)xr[k + 1], (double)W[(size_t)(k + 1) * 64 + e], a1);
            a2 = fma((double)xr[k + 2], (double)W[(size_t)(k + 2) * 64 + e], a2);
            a3 = fma((double)xr[k + 3], (double)W[(size_t)(k + 3) * 64 + e], a3);
        }
        red[tid] = (a0 + a1) + (a2 + a3);
        __syncthreads();
        if (tid < 128) red[tid] += red[tid + 128];
        __syncthreads();
        if (tid < 64) {
            const double z = red[tid] + red[tid + 64] + (double)b[e];
            double v1 = z, v2 = -1e300;
            int i1 = e, i2 = 1 << 30;
#pragma unroll
            for (int m = 1; m < 64; m <<= 1) {
                const double w1 = __shfl_xor(v1, m, 64); const int j1 = __shfl_xor(i1, m, 64);
                const double w2 = __shfl_xor(v2, m, 64); const int j2 = __shfl_xor(i2, m, 64);
                if (betterd(w1, j1, v1, i1)) {
                    double nv2; int ni2;
                    if (betterd(v1, i1, w2, j2)) { nv2 = v1; ni2 = i1; }
                    else                         { nv2 = w2; ni2 = j2; }
                    v1 = w1; i1 = j1; v2 = nv2; i2 = ni2;
                } else if (betterd(w1, j1, v2, i2)) { v2 = w1; i2 = j1; }
            }
            float sl = expf((float)(z - v1));
            float ssum = sl;
#pragma unroll
            for (int m = 1; m < 64; m <<= 1) ssum += __shfl_xor(ssum, m, 64);
            const float inv = 1.0f / ssum;
            if (e == 0) {
                const float s1 = fminf(fmaxf(inv, EPS_), 1.0f - EPS_);
                const float s2 = fminf(fmaxf(expf((float)(v2 - v1)) * inv, EPS_), 1.0f - EPS_);
                ts[row * 2 + 0] = s1;
                ts[row * 2 + 1] = s2;
                sel[row * 2 + 0] = i1;
                sel[row * 2 + 1] = i2;
            }
        }
        __syncthreads();
    }
}

// per-64-slot-chunk expert counts (transposed layout) + global histogram
__global__ void hist_chunks(const int* __restrict__ sel, int nchunks,
                            int* __restrict__ hist, int* __restrict__ cnt2)
{
    __shared__ int cnt[64];
    const int lane = threadIdx.x;   // 64
    const int c = blockIdx.x;
    cnt[lane] = 0;
    __syncthreads();
    const int ex = sel[c * 64 + lane];
    atomicAdd(&cnt[ex], 1);
    __syncthreads();
    cnt2[(size_t)lane * nchunks + c] = cnt[lane];   // [e][c] for coalesced scan
    if (cnt[lane]) atomicAdd(&hist[lane], cnt[lane]);
}

// per-batch rz sums (deterministic tree)
__global__ void rz_batch(const float* __restrict__ rzrow,
                         const int* __restrict__ bs_p, const int* __restrict__ sl_p,
                         double* __restrict__ bsum)
{
    __shared__ double red[256];
    const int nb = bs_p[0];
    const int seq = sl_p[0];
    for (int bb = blockIdx.x; bb < nb; bb += gridDim.x) {
        double s = 0.0;
        for (int i = threadIdx.x; i < seq; i += 256)
            s += (double)rzrow[(size_t)bb * seq + i];
        red[threadIdx.x] = s;
        __syncthreads();
        for (int st = 128; st > 0; st >>= 1) {
            if (threadIdx.x < st) red[threadIdx.x] += red[threadIdx.x + st];
            __syncthreads();
        }
        if (threadIdx.x == 0) bsum[bb] = red[0];
        __syncthreads();
    }
}

// expert starts (exclusive scan of hist) + out_cnt + rz finalize
__global__ void combine(const int* __restrict__ hist,
                        int* __restrict__ estart,
                        const double* __restrict__ bsum,
                        const int* __restrict__ bs_p,
                        float* __restrict__ out_cnt, float* __restrict__ out_rz)
{
    const int e = threadIdx.x;   // 64
    const int c0 = hist[e];
    int incl = c0;
#pragma unroll
    for (int m = 1; m < 64; m <<= 1) {
        const int w = __shfl_up(incl, m, 64);
        if (e >= m) incl += w;
    }
    estart[e] = incl - c0;
    out_cnt[e] = (float)c0;
    if (e == 0) {
        const int nb = bs_p[0];
        double a = 0.0;
        for (int i = 0; i < nb; ++i) a += log(bsum[i]);
        out_rz[0] = (float)(a / nb);
    }
}

// parallel per-expert scan over chunks
__global__ __launch_bounds__(1024)
void chunk_scan(const int* __restrict__ cnt2, const int* __restrict__ estart,
                int nchunks, int* __restrict__ cbase)
{
    __shared__ int sc[1024];
    const int e = blockIdx.x;    // 64 blocks
    const int t = threadIdx.x;   // 1024
    const int v = (t < nchunks) ? cnt2[(size_t)e * nchunks + t] : 0;
    sc[t] = v;
    __syncthreads();
#pragma unroll
    for (int off = 1; off < 1024; off <<= 1) {
        const int add = (t >= off) ? sc[t - off] : 0;
        __syncthreads();
        sc[t] += add;
        __syncthreads();
    }
    if (t < nchunks)
        cbase[(size_t)t * 64 + e] = estart[e] + sc[t] - v;   // exclusive
}

// stable scatter per 64-slot chunk
__global__ void scatter(const int* __restrict__ sel, const float* __restrict__ ts,
                        const int* __restrict__ cbase,
                        float* __restrict__ out_sc, float* __restrict__ out_idx)
{
    __shared__ int shx[64];
    const int lane = threadIdx.x;   // 64
    const int c = blockIdx.x;
    const int idx = c * 64 + lane;
    const int ex = sel[idx];
    shx[lane] = ex;
    __syncthreads();
    int pre = 0;
#pragma unroll
    for (int j = 0; j < 64; ++j) pre += (int)((j < lane) && (shx[j] == ex));
    const int pos = cbase[c * 64 + ex] + pre;
    out_sc[pos]  = ts[idx];
    out_idx[pos] = (float)(idx >> 1);
}

extern "C" void kernel_launch(void* const* d_in, const int* in_sizes, int n_in,
                              void* d_out, int out_size, void* d_ws, size_t ws_size,
                              hipStream_t stream)
{
    const float* x = (const float*)d_in[0];
    const float* W = (const float*)d_in[1];
    const float* b = (const float*)d_in[2];
    const int* bs_p = (const int*)d_in[3];
    const int* sl_p = (const int*)d_in[4];

    const int E   = in_sizes[2];           // 64
    const int dim = in_sizes[1] / E;       // 2048
    const int N   = in_sizes[0] / dim;     // 16384
    const int total = N * 2;               // slots
    const int nchunks = total / 64;        // 512

    char* ws = (char*)d_ws;
    size_t off = 0;
    int*    hist     = (int*)(ws + off); off += 256;
    double* bsum     = (double*)(ws + off); off += 512;
    int*    nflags   = (int*)(ws + off); off += 256;
    int*    estart   = (int*)(ws + off); off += 256;
    float*  ts       = (float*)(ws + off); off += (size_t)total * 4;
    int*    sel      = (int*)(ws + off); off += (size_t)total * 4;
    int*    flaglist = (int*)(ws + off); off += (size_t)N * 4;
    float*  rzrow    = (float*)(ws + off); off += (size_t)N * 4;
    int*    cnt2     = (int*)(ws + off); off += (size_t)nchunks * 64 * 4;
    int*    cbase    = (int*)(ws + off); off += (size_t)nchunks * 64 * 4;

    // pick largest ksplit whose zpart fits the workspace
    int ksplit = 8;
    while (ksplit > 1 &&
           off + (size_t)ksplit * N * 64 * sizeof(float) > ws_size)
        ksplit >>= 1;
    float* zpart = (float*)(ws + off);

    float* out_sc  = (float*)d_out;
    float* out_idx = out_sc + total;
    float* out_cnt = out_idx + total;
    float* out_rz  = out_cnt + E;

    hipMemsetAsync(ws, 0, 1280, stream);

    const int rgs = N / 64;  // 256 row groups
    hipLaunchKernelGGL((gemm_rows<32>), dim3(rgs * ksplit), dim3(256), 0, stream,
                       x, W, dim, N, ksplit, rgs, zpart);
    hipLaunchKernelGGL(epilogue, dim3(N / 256), dim3(256), 0, stream,
                       zpart, b, N, ksplit, ts, sel, rzrow, nflags, flaglist);
    hipLaunchKernelGGL(fixup, dim3(512), dim3(256), 0, stream,
                       x, W, b, dim, nflags, flaglist, ts, sel);
    hipLaunchKernelGGL(hist_chunks, dim3(nchunks), dim3(64), 0, stream,
                       sel, nchunks, hist, cnt2);
    hipLaunchKernelGGL(rz_batch, dim3(64), dim3(256), 0, stream,
                       rzrow, bs_p, sl_p, bsum);
    hipLaunchKernelGGL(combine, dim3(1), dim3(64), 0, stream,
                       hist, estart, bsum, bs_p, out_cnt, out_rz);
    hipLaunchKernelGGL(chunk_scan, dim3(64), dim3(1024), 0, stream,
                       cnt2, estart, nchunks, cbase);
    hipLaunchKernelGGL(scatter, dim3(nchunks), dim3(64), 0, stream,
                       sel, ts, cbase, out_sc, out_idx);
}

// Round 7
// 215.264 us; speedup vs baseline: 1.8282x; 1.8282x over previous
//
#include <hip/hip_runtime.h>
#include <math.h>

#define EPS_ 1e-10f
#define MARGIN 2e-3f

__device__ __forceinline__ bool betterd(double v, int i, double w, int j) {
    return (v > w) || (v == w && i < j);
}

// ---------------------------------------------------------------------------
// GEMM: block = 256 thr (4 waves) = 64 rows x 64 experts, one K-slice.
// lane = row; wave w owns experts [16w, 16w+16): acc[16] per thread.
// e0 goes through readfirstlane so W addresses are SGPR-valued -> the
// compiler scalarizes W loads (s_load_dwordx16 per k, LGKM pipe) and FMAs
// read W straight from SGPRs. x staged per-block into LDS transposed
// (conflict-free broadcast reads), register-double-buffered across windows.
// Grid = ksplit * (N/64) = 2048 blocks -> 8 blocks/CU, 8 waves/SIMD.
// zpart[ks][e][row] (lane-coalesced stores).
// ---------------------------------------------------------------------------
template<int KW>
__global__ __launch_bounds__(256, 8)
void gemm_rows(const float* __restrict__ x, const float* __restrict__ W,
               int dim, int N, int ks_count, int rgs,
               float* __restrict__ zpart)
{
    __shared__ float xT[KW][65];   // [k][row]; pad -> 2-way max (free)

    const int tid  = threadIdx.x;
    const int lane = tid & 63;                                   // row
    const int e0   = __builtin_amdgcn_readfirstlane((tid >> 6) << 4);
    const int ks = blockIdx.x / rgs;
    const int rg = blockIdx.x % rgs;
    const int r0 = rg * 64;
    const int kslice = dim / ks_count;
    const int k0 = ks * kslice;

    // staging lanes: thread covers 8 floats of one row
    const int srow = tid >> 2;           // 0..63
    const int sk8  = (tid & 3) * 8;      // 0,8,16,24

    float acc[16];
#pragma unroll
    for (int e = 0; e < 16; ++e) acc[e] = 0.0f;

    const float* xsrc = x + (size_t)(r0 + srow) * dim + k0 + sk8;
    const float* wbase = W + e0;         // SGPR-uniform base

    float4 va = *(const float4*)(xsrc);
    float4 vb = *(const float4*)(xsrc + 4);

    for (int w = 0; w < kslice; w += KW) {
        xT[sk8 + 0][srow] = va.x; xT[sk8 + 1][srow] = va.y;
        xT[sk8 + 2][srow] = va.z; xT[sk8 + 3][srow] = va.w;
        xT[sk8 + 4][srow] = vb.x; xT[sk8 + 5][srow] = vb.y;
        xT[sk8 + 6][srow] = vb.z; xT[sk8 + 7][srow] = vb.w;
        __syncthreads();

        if (w + KW < kslice) {
            va = *(const float4*)(xsrc + w + KW);
            vb = *(const float4*)(xsrc + w + KW + 4);
        }

        const float* wpk = wbase + (size_t)(k0 + w) * 64;
#pragma unroll 4
        for (int k = 0; k < KW; ++k) {
            const float xv = xT[k][lane];
            const float* wk = wpk + (size_t)k * 64;   // uniform -> s_load
#pragma unroll
            for (int j = 0; j < 16; ++j)
                acc[j] = fmaf(xv, wk[j], acc[j]);
        }
        __syncthreads();
    }

    float* zp = zpart + ((size_t)ks * 64 + e0) * N + r0 + lane;
#pragma unroll
    for (int e = 0; e < 16; ++e)
        zp[(size_t)e * N] = acc[e];
}

// ---------------------------------------------------------------------------
// Epilogue: thread = row. Sum K-split partials (fixed order), + bias,
// in-thread top-2 (strict > => lowest index on ties), 3rd-max gap flag,
// softmax, rz row value. No cross-lane ops.
// ---------------------------------------------------------------------------
__global__ __launch_bounds__(256)
void epilogue(const float* __restrict__ zpart, const float* __restrict__ b,
              int N, int ks_count,
              float* __restrict__ ts, int* __restrict__ sel,
              float* __restrict__ rzrow,
              int* __restrict__ nflags, int* __restrict__ flaglist)
{
    const int row = blockIdx.x * 256 + threadIdx.x;
    if (row >= N) return;

    float acc[64];
#pragma unroll
    for (int e = 0; e < 64; ++e) acc[e] = b[e];
    for (int ks = 0; ks < ks_count; ++ks) {
        const float* zp = zpart + ((size_t)ks * 64) * N + row;
#pragma unroll
        for (int e = 0; e < 64; ++e) acc[e] += zp[(size_t)e * N];
    }

    float v1 = -3.4e38f, v2 = -3.4e38f;
    int i1 = 0, i2 = 0;
#pragma unroll
    for (int e = 0; e < 64; ++e) {
        const float v = acc[e];
        if (v > v1)      { v2 = v1; i2 = i1; v1 = v; i1 = e; }
        else if (v > v2) { v2 = v;  i2 = e; }
    }
    float m3 = -3.4e38f;
#pragma unroll
    for (int e = 0; e < 64; ++e) {
        const float v = acc[e];
        const bool skip = (e == i1) || (e == i2);
        m3 = skip ? m3 : fmaxf(m3, v);
    }

    float ssum = 0.0f;
#pragma unroll
    for (int e = 0; e < 64; ++e) { acc[e] = expf(acc[e] - v1); ssum += acc[e]; }
    const float inv = 1.0f / ssum;
    float srz = 0.0f;
#pragma unroll
    for (int e = 0; e < 64; ++e) {
        float sc = fminf(fmaxf(acc[e] * inv, EPS_), 1.0f - EPS_);
        srz += sc / (1.0f - sc);
    }

    const float s1 = fminf(fmaxf(inv, EPS_), 1.0f - EPS_);
    const float s2 = fminf(fmaxf(expf(v2 - v1) * inv, EPS_), 1.0f - EPS_);
    ts[row * 2 + 0] = s1;
    ts[row * 2 + 1] = s2;
    sel[row * 2 + 0] = i1;
    sel[row * 2 + 1] = i2;
    rzrow[row] = srz;
    if ((v1 - v2) < MARGIN || (v2 - m3) < MARGIN) {
        const int slot = atomicAdd(nflags, 1);
        flaglist[slot] = row;
    }
}

// ---------------------------------------------------------------------------
// fp64 recompute of flagged near-tie rows (4 independent accumulator chains).
// ---------------------------------------------------------------------------
__global__ __launch_bounds__(256)
void fixup(const float* __restrict__ x, const float* __restrict__ W,
           const float* __restrict__ b, int dim,
           const int* __restrict__ nflags, const int* __restrict__ flaglist,
           float* __restrict__ ts, int* __restrict__ sel)
{
    __shared__ double red[256];
    const int tid = threadIdx.x;
    const int e = tid & 63;
    const int q = tid >> 6;
    const int nf = *nflags;
    const int quarter = dim >> 2;

    for (int f = blockIdx.x; f < nf; f += gridDim.x) {
        const int row = flaglist[f];
        const float* xr = x + (size_t)row * dim;
        const int k0 = q * quarter;
        double a0 = 0.0, a1 = 0.0, a2 = 0.0, a3 = 0.0;
        for (int k = k0; k < k0 + quarter; k += 4) {
            a0 = fma((double)xr[k + 0], (double)W[(size_t)(k + 0) * 64 + e], a0);
            a1 = fma((double)xr[k + 1], (double)W[(size_t)(k + 1) * 64 + e], a1);
            a2 = fma((double)xr[k + 2], (double)W[(size_t)(k + 2) * 64 + e], a2);
            a3 = fma((double)xr[k + 3], (double)W[(size_t)(k + 3) * 64 + e], a3);
        }
        red[tid] = (a0 + a1) + (a2 + a3);
        __syncthreads();
        if (tid < 128) red[tid] += red[tid + 128];
        __syncthreads();
        if (tid < 64) {
            const double z = red[tid] + red[tid + 64] + (double)b[e];
            double v1 = z, v2 = -1e300;
            int i1 = e, i2 = 1 << 30;
#pragma unroll
            for (int m = 1; m < 64; m <<= 1) {
                const double w1 = __shfl_xor(v1, m, 64); const int j1 = __shfl_xor(i1, m, 64);
                const double w2 = __shfl_xor(v2, m, 64); const int j2 = __shfl_xor(i2, m, 64);
                if (betterd(w1, j1, v1, i1)) {
                    double nv2; int ni2;
                    if (betterd(v1, i1, w2, j2)) { nv2 = v1; ni2 = i1; }
                    else                         { nv2 = w2; ni2 = j2; }
                    v1 = w1; i1 = j1; v2 = nv2; i2 = ni2;
                } else if (betterd(w1, j1, v2, i2)) { v2 = w1; i2 = j1; }
            }
            float sl = expf((float)(z - v1));
            float ssum = sl;
#pragma unroll
            for (int m = 1; m < 64; m <<= 1) ssum += __shfl_xor(ssum, m, 64);
            const float inv = 1.0f / ssum;
            if (e == 0) {
                const float s1 = fminf(fmaxf(inv, EPS_), 1.0f - EPS_);
                const float s2 = fminf(fmaxf(expf((float)(v2 - v1)) * inv, EPS_), 1.0f - EPS_);
                ts[row * 2 + 0] = s1;
                ts[row * 2 + 1] = s2;
                sel[row * 2 + 0] = i1;
                sel[row * 2 + 1] = i2;
            }
        }
        __syncthreads();
    }
}

// per-64-slot-chunk expert counts (transposed layout) + global histogram
__global__ void hist_chunks(const int* __restrict__ sel, int nchunks,
                            int* __restrict__ hist, int* __restrict__ cnt2)
{
    __shared__ int cnt[64];
    const int lane = threadIdx.x;   // 64
    const int c = blockIdx.x;
    cnt[lane] = 0;
    __syncthreads();
    const int ex = sel[c * 64 + lane];
    atomicAdd(&cnt[ex], 1);
    __syncthreads();
    cnt2[(size_t)lane * nchunks + c] = cnt[lane];   // [e][c] for coalesced scan
    if (cnt[lane]) atomicAdd(&hist[lane], cnt[lane]);
}

// per-batch rz sums (deterministic tree)
__global__ void rz_batch(const float* __restrict__ rzrow,
                         const int* __restrict__ bs_p, const int* __restrict__ sl_p,
                         double* __restrict__ bsum)
{
    __shared__ double red[256];
    const int nb = bs_p[0];
    const int seq = sl_p[0];
    for (int bb = blockIdx.x; bb < nb; bb += gridDim.x) {
        double s = 0.0;
        for (int i = threadIdx.x; i < seq; i += 256)
            s += (double)rzrow[(size_t)bb * seq + i];
        red[threadIdx.x] = s;
        __syncthreads();
        for (int st = 128; st > 0; st >>= 1) {
            if (threadIdx.x < st) red[threadIdx.x] += red[threadIdx.x + st];
            __syncthreads();
        }
        if (threadIdx.x == 0) bsum[bb] = red[0];
        __syncthreads();
    }
}

// expert starts (exclusive scan of hist) + out_cnt + rz finalize
__global__ void combine(const int* __restrict__ hist,
                        int* __restrict__ estart,
                        const double* __restrict__ bsum,
                        const int* __restrict__ bs_p,
                        float* __restrict__ out_cnt, float* __restrict__ out_rz)
{
    const int e = threadIdx.x;   // 64
    const int c0 = hist[e];
    int incl = c0;
#pragma unroll
    for (int m = 1; m < 64; m <<= 1) {
        const int w = __shfl_up(incl, m, 64);
        if (e >= m) incl += w;
    }
    estart[e] = incl - c0;
    out_cnt[e] = (float)c0;
    if (e == 0) {
        const int nb = bs_p[0];
        double a = 0.0;
        for (int i = 0; i < nb; ++i) a += log(bsum[i]);
        out_rz[0] = (float)(a / nb);
    }
}

// parallel per-expert scan over chunks
__global__ __launch_bounds__(1024)
void chunk_scan(const int* __restrict__ cnt2, const int* __restrict__ estart,
                int nchunks, int* __restrict__ cbase)
{
    __shared__ int sc[1024];
    const int e = blockIdx.x;    // 64 blocks
    const int t = threadIdx.x;   // 1024
    const int v = (t < nchunks) ? cnt2[(size_t)e * nchunks + t] : 0;
    sc[t] = v;
    __syncthreads();
#pragma unroll
    for (int off = 1; off < 1024; off <<= 1) {
        const int add = (t >= off) ? sc[t - off] : 0;
        __syncthreads();
        sc[t] += add;
        __syncthreads();
    }
    if (t < nchunks)
        cbase[(size_t)t * 64 + e] = estart[e] + sc[t] - v;   // exclusive
}

// stable scatter per 64-slot chunk
__global__ void scatter(const int* __restrict__ sel, const float* __restrict__ ts,
                        const int* __restrict__ cbase,
                        float* __restrict__ out_sc, float* __restrict__ out_idx)
{
    __shared__ int shx[64];
    const int lane = threadIdx.x;   // 64
    const int c = blockIdx.x;
    const int idx = c * 64 + lane;
    const int ex = sel[idx];
    shx[lane] = ex;
    __syncthreads();
    int pre = 0;
#pragma unroll
    for (int j = 0; j < 64; ++j) pre += (int)((j < lane) && (shx[j] == ex));
    const int pos = cbase[c * 64 + ex] + pre;
    out_sc[pos]  = ts[idx];
    out_idx[pos] = (float)(idx >> 1);
}

extern "C" void kernel_launch(void* const* d_in, const int* in_sizes, int n_in,
                              void* d_out, int out_size, void* d_ws, size_t ws_size,
                              hipStream_t stream)
{
    const float* x = (const float*)d_in[0];
    const float* W = (const float*)d_in[1];
    const float* b = (const float*)d_in[2];
    const int* bs_p = (const int*)d_in[3];
    const int* sl_p = (const int*)d_in[4];

    const int E   = in_sizes[2];           // 64
    const int dim = in_sizes[1] / E;       // 2048
    const int N   = in_sizes[0] / dim;     // 16384
    const int total = N * 2;               // slots
    const int nchunks = total / 64;        // 512

    char* ws = (char*)d_ws;
    size_t off = 0;
    int*    hist     = (int*)(ws + off); off += 256;
    double* bsum     = (double*)(ws + off); off += 512;
    int*    nflags   = (int*)(ws + off); off += 256;
    int*    estart   = (int*)(ws + off); off += 256;
    float*  ts       = (float*)(ws + off); off += (size_t)total * 4;
    int*    sel      = (int*)(ws + off); off += (size_t)total * 4;
    int*    flaglist = (int*)(ws + off); off += (size_t)N * 4;
    float*  rzrow    = (float*)(ws + off); off += (size_t)N * 4;
    int*    cnt2     = (int*)(ws + off); off += (size_t)nchunks * 64 * 4;
    int*    cbase    = (int*)(ws + off); off += (size_t)nchunks * 64 * 4;

    // pick largest ksplit whose zpart fits the workspace
    int ksplit = 8;
    while (ksplit > 1 &&
           off + (size_t)ksplit * N * 64 * sizeof(float) > ws_size)
        ksplit >>= 1;
    float* zpart = (float*)(ws + off);

    float* out_sc  = (float*)d_out;
    float* out_idx = out_sc + total;
    float* out_cnt = out_idx + total;
    float* out_rz  = out_cnt + E;

    hipMemsetAsync(ws, 0, 1280, stream);

    const int rgs = N / 64;  // 256 row groups
    hipLaunchKernelGGL((gemm_rows<32>), dim3(rgs * ksplit), dim3(256), 0, stream,
                       x, W, dim, N, ksplit, rgs, zpart);
    hipLaunchKernelGGL(epilogue, dim3(N / 256), dim3(256), 0, stream,
                       zpart, b, N, ksplit, ts, sel, rzrow, nflags, flaglist);
    hipLaunchKernelGGL(fixup, dim3(512), dim3(256), 0, stream,
                       x, W, b, dim, nflags, flaglist, ts, sel);
    hipLaunchKernelGGL(hist_chunks, dim3(nchunks), dim3(64), 0, stream,
                       sel, nchunks, hist, cnt2);
    hipLaunchKernelGGL(rz_batch, dim3(64), dim3(256), 0, stream,
                       rzrow, bs_p, sl_p, bsum);
    hipLaunchKernelGGL(combine, dim3(1), dim3(64), 0, stream,
                       hist, estart, bsum, bs_p, out_cnt, out_rz);
    hipLaunchKernelGGL(chunk_scan, dim3(64), dim3(1024), 0, stream,
                       cnt2, estart, nchunks, cbase);
    hipLaunchKernelGGL(scatter, dim3(nchunks), dim3(64), 0, stream,
                       sel, ts, cbase, out_sc, out_idx);
}

// Round 8
// 131.729 us; speedup vs baseline: 2.9876x; 1.6341x over previous
//
#include <hip/hip_runtime.h>
#include <math.h>

#define EPS_ 1e-10f
#define MARGIN 2e-3f

__device__ __forceinline__ bool betterd(double v, int i, double w, int j) {
    return (v > w) || (v == w && i < j);
}

// ---------------------------------------------------------------------------
// GEMM: block = 256 thr (4 waves) = 64 rows x 64 experts, one K-slice.
// lane = row; wave w owns experts [16w,16w+16) via readfirstlane -> W loads
// scalarize to s_load_dwordx16. Key fix vs R7: x window is pre-read into
// registers (xv[16]) BEFORE the s_load/FMA loop, so the per-k lgkmcnt waits
// cover only SMEM (no LDS/SMEM lgkmcnt conflation), and the LDS is
// double-buffered with ONE barrier per window.
// Grid = ksplit * (N/64) = 2048 blocks -> 8 blocks/CU, 8 waves/SIMD.
// zpart[ks][e][row] (lane-coalesced stores).
// ---------------------------------------------------------------------------
template<int KW>
__global__ __launch_bounds__(256, 8)
void gemm_rows(const float* __restrict__ x, const float* __restrict__ W,
               int dim, int N, int ks_count, int rgs,
               float* __restrict__ zpart)
{
    __shared__ float xT[2][KW][65];   // [buf][k][row]; pad 65

    const int tid  = threadIdx.x;
    const int lane = tid & 63;                                   // row
    const int e0   = __builtin_amdgcn_readfirstlane((tid >> 6) << 4);
    const int ks = blockIdx.x / rgs;
    const int rg = blockIdx.x % rgs;
    const int r0 = rg * 64;
    const int kslice = dim / ks_count;
    const int k0 = ks * kslice;
    const int nwin = kslice / KW;

    // staging: 256 threads x one float4 = 64 rows x 16 k
    const int srow = tid >> 2;           // 0..63
    const int sk4  = (tid & 3) * 4;      // 0,4,8,12

    float acc[16];
#pragma unroll
    for (int e = 0; e < 16; ++e) acc[e] = 0.0f;

    const float* xsrc  = x + (size_t)(r0 + srow) * dim + k0 + sk4;
    const float* wbase = W + e0;         // SGPR-uniform base

    // prologue: stage window 0, prefetch window 1
    float4 va = *(const float4*)xsrc;
    xT[0][sk4 + 0][srow] = va.x; xT[0][sk4 + 1][srow] = va.y;
    xT[0][sk4 + 2][srow] = va.z; xT[0][sk4 + 3][srow] = va.w;
    float4 vn;
    if (nwin > 1) vn = *(const float4*)(xsrc + KW);
    __syncthreads();

    int cur = 0;
    for (int w = 0; w < nwin; ++w) {
        // pre-read x window into registers (static indices)
        float xv[KW];
#pragma unroll
        for (int k = 0; k < KW; ++k) xv[k] = xT[cur][k][lane];

        // stage next window into the other buffer
        if (w + 1 < nwin) {
            xT[cur ^ 1][sk4 + 0][srow] = vn.x;
            xT[cur ^ 1][sk4 + 1][srow] = vn.y;
            xT[cur ^ 1][sk4 + 2][srow] = vn.z;
            xT[cur ^ 1][sk4 + 3][srow] = vn.w;
            if (w + 2 < nwin)
                vn = *(const float4*)(xsrc + (size_t)(w + 2) * KW);
        }
        __syncthreads();   // drains lgkm: xv ready, buffers consistent

        // pure SMEM + FMA loop: lgkm waits now cover only s_loads
        const float* wpk = wbase + (size_t)(k0 + w * KW) * 64;
#pragma unroll 4
        for (int k = 0; k < KW; ++k) {
            const float* wk = wpk + (size_t)k * 64;   // uniform -> s_load_x16
#pragma unroll
            for (int j = 0; j < 16; ++j)
                acc[j] = fmaf(xv[k], wk[j], acc[j]);
        }
        cur ^= 1;
    }

    float* zp = zpart + ((size_t)ks * 64 + e0) * N + r0 + lane;
#pragma unroll
    for (int e = 0; e < 16; ++e)
        zp[(size_t)e * N] = acc[e];
}

// ---------------------------------------------------------------------------
// Parallel K-split reduce: z[e][row] = sum_ks zpart[ks][e][row] + b[e].
// thread t -> (equad = t/N, row = t%N); fully coalesced loads and stores.
// Grid = N*16/256 = 1024 blocks.
// ---------------------------------------------------------------------------
__global__ __launch_bounds__(256)
void zred(const float* __restrict__ zpart, const float* __restrict__ b,
          int N, int ks_count, float* __restrict__ z)
{
    const int t   = blockIdx.x * 256 + threadIdx.x;
    const int row = t % N;
    const int eq  = t / N;            // 0..15
    float s0 = 0.f, s1 = 0.f, s2 = 0.f, s3 = 0.f;
    for (int ks = 0; ks < ks_count; ++ks) {
        const float* zp = zpart + ((size_t)ks * 64 + eq * 4) * N + row;
        s0 += zp[0 * (size_t)N];
        s1 += zp[1 * (size_t)N];
        s2 += zp[2 * (size_t)N];
        s3 += zp[3 * (size_t)N];
    }
    float* zo = z + (size_t)(eq * 4) * N + row;
    zo[0 * (size_t)N] = s0 + b[eq * 4 + 0];
    zo[1 * (size_t)N] = s1 + b[eq * 4 + 1];
    zo[2 * (size_t)N] = s2 + b[eq * 4 + 2];
    zo[3 * (size_t)N] = s3 + b[eq * 4 + 3];
}

// ---------------------------------------------------------------------------
// Epilogue: thread = row. Reads z[e][row] (4MB), in-thread top-2
// (strict > => lowest index on ties), 3rd-max gap flag, softmax, rz.
// ---------------------------------------------------------------------------
__global__ __launch_bounds__(256)
void epilogue(const float* __restrict__ z, int N,
              float* __restrict__ ts, int* __restrict__ sel,
              float* __restrict__ rzrow,
              int* __restrict__ nflags, int* __restrict__ flaglist)
{
    const int row = blockIdx.x * 256 + threadIdx.x;
    if (row >= N) return;

    float acc[64];
#pragma unroll
    for (int e = 0; e < 64; ++e) acc[e] = z[(size_t)e * N + row];

    float v1 = -3.4e38f, v2 = -3.4e38f;
    int i1 = 0, i2 = 0;
#pragma unroll
    for (int e = 0; e < 64; ++e) {
        const float v = acc[e];
        if (v > v1)      { v2 = v1; i2 = i1; v1 = v; i1 = e; }
        else if (v > v2) { v2 = v;  i2 = e; }
    }
    float m3 = -3.4e38f;
#pragma unroll
    for (int e = 0; e < 64; ++e) {
        const float v = acc[e];
        const bool skip = (e == i1) || (e == i2);
        m3 = skip ? m3 : fmaxf(m3, v);
    }

    float ssum = 0.0f;
#pragma unroll
    for (int e = 0; e < 64; ++e) { acc[e] = expf(acc[e] - v1); ssum += acc[e]; }
    const float inv = 1.0f / ssum;
    float srz = 0.0f;
#pragma unroll
    for (int e = 0; e < 64; ++e) {
        float sc = fminf(fmaxf(acc[e] * inv, EPS_), 1.0f - EPS_);
        srz += sc / (1.0f - sc);
    }

    const float s1 = fminf(fmaxf(inv, EPS_), 1.0f - EPS_);
    const float s2 = fminf(fmaxf(expf(v2 - v1) * inv, EPS_), 1.0f - EPS_);
    ts[row * 2 + 0] = s1;
    ts[row * 2 + 1] = s2;
    sel[row * 2 + 0] = i1;
    sel[row * 2 + 1] = i2;
    rzrow[row] = srz;
    if ((v1 - v2) < MARGIN || (v2 - m3) < MARGIN) {
        const int slot = atomicAdd(nflags, 1);
        flaglist[slot] = row;
    }
}

// ---------------------------------------------------------------------------
// fp64 recompute of flagged near-tie rows. 1024 thr = 64 e x 16 K-slices,
// 4 independent chains of 32 per slice.
// ---------------------------------------------------------------------------
__global__ __launch_bounds__(1024)
void fixup(const float* __restrict__ x, const float* __restrict__ W,
           const float* __restrict__ b, int dim,
           const int* __restrict__ nflags, const int* __restrict__ flaglist,
           float* __restrict__ ts, int* __restrict__ sel)
{
    __shared__ double red[1024];
    const int tid = threadIdx.x;
    const int e = tid & 63;
    const int q = tid >> 6;              // 0..15
    const int nf = *nflags;
    const int slice = dim >> 4;          // 128

    for (int f = blockIdx.x; f < nf; f += gridDim.x) {
        const int row = flaglist[f];
        const float* xr = x + (size_t)row * dim;
        const int k0 = q * slice;
        double a0 = 0.0, a1 = 0.0, a2 = 0.0, a3 = 0.0;
        for (int k = k0; k < k0 + slice; k += 4) {
            a0 = fma((double)xr[k + 0], (double)W[(size_t)(k + 0) * 64 + e], a0);
            a1 = fma((double)xr[k + 1], (double)W[(size_t)(k + 1) * 64 + e], a1);
            a2 = fma((double)xr[k + 2], (double)W[(size_t)(k + 2) * 64 + e], a2);
            a3 = fma((double)xr[k + 3], (double)W[(size_t)(k + 3) * 64 + e], a3);
        }
        red[tid] = (a0 + a1) + (a2 + a3);
        __syncthreads();
        for (int st = 512; st >= 64; st >>= 1) {
            if (tid < st) red[tid] += red[tid + st];
            __syncthreads();
        }
        if (tid < 64) {
            const double z = red[tid] + (double)b[e];
            double v1 = z, v2 = -1e300;
            int i1 = e, i2 = 1 << 30;
#pragma unroll
            for (int m = 1; m < 64; m <<= 1) {
                const double w1 = __shfl_xor(v1, m, 64); const int j1 = __shfl_xor(i1, m, 64);
                const double w2 = __shfl_xor(v2, m, 64); const int j2 = __shfl_xor(i2, m, 64);
                if (betterd(w1, j1, v1, i1)) {
                    double nv2; int ni2;
                    if (betterd(v1, i1, w2, j2)) { nv2 = v1; ni2 = i1; }
                    else                         { nv2 = w2; ni2 = j2; }
                    v1 = w1; i1 = j1; v2 = nv2; i2 = ni2;
                } else if (betterd(w1, j1, v2, i2)) { v2 = w1; i2 = j1; }
            }
            float sl = expf((float)(z - v1));
            float ssum = sl;
#pragma unroll
            for (int m = 1; m < 64; m <<= 1) ssum += __shfl_xor(ssum, m, 64);
            const float inv = 1.0f / ssum;
            if (e == 0) {
                const float s1 = fminf(fmaxf(inv, EPS_), 1.0f - EPS_);
                const float s2 = fminf(fmaxf(expf((float)(v2 - v1)) * inv, EPS_), 1.0f - EPS_);
                ts[row * 2 + 0] = s1;
                ts[row * 2 + 1] = s2;
                sel[row * 2 + 0] = i1;
                sel[row * 2 + 1] = i2;
            }
        }
        __syncthreads();
    }
}

// per-64-slot-chunk expert counts (transposed layout) + global histogram
__global__ void hist_chunks(const int* __restrict__ sel, int nchunks,
                            int* __restrict__ hist, int* __restrict__ cnt2)
{
    __shared__ int cnt[64];
    const int lane = threadIdx.x;   // 64
    const int c = blockIdx.x;
    cnt[lane] = 0;
    __syncthreads();
    const int ex = sel[c * 64 + lane];
    atomicAdd(&cnt[ex], 1);
    __syncthreads();
    cnt2[(size_t)lane * nchunks + c] = cnt[lane];
    if (cnt[lane]) atomicAdd(&hist[lane], cnt[lane]);
}

// per-batch rz sums (deterministic tree)
__global__ void rz_batch(const float* __restrict__ rzrow,
                         const int* __restrict__ bs_p, const int* __restrict__ sl_p,
                         double* __restrict__ bsum)
{
    __shared__ double red[256];
    const int nb = bs_p[0];
    const int seq = sl_p[0];
    for (int bb = blockIdx.x; bb < nb; bb += gridDim.x) {
        double s = 0.0;
        for (int i = threadIdx.x; i < seq; i += 256)
            s += (double)rzrow[(size_t)bb * seq + i];
        red[threadIdx.x] = s;
        __syncthreads();
        for (int st = 128; st > 0; st >>= 1) {
            if (threadIdx.x < st) red[threadIdx.x] += red[threadIdx.x + st];
            __syncthreads();
        }
        if (threadIdx.x == 0) bsum[bb] = red[0];
        __syncthreads();
    }
}

// expert starts (exclusive scan of hist) + out_cnt + rz finalize
__global__ void combine(const int* __restrict__ hist,
                        int* __restrict__ estart,
                        const double* __restrict__ bsum,
                        const int* __restrict__ bs_p,
                        float* __restrict__ out_cnt, float* __restrict__ out_rz)
{
    const int e = threadIdx.x;   // 64
    const int c0 = hist[e];
    int incl = c0;
#pragma unroll
    for (int m = 1; m < 64; m <<= 1) {
        const int w = __shfl_up(incl, m, 64);
        if (e >= m) incl += w;
    }
    estart[e] = incl - c0;
    out_cnt[e] = (float)c0;
    if (e == 0) {
        const int nb = bs_p[0];
        double a = 0.0;
        for (int i = 0; i < nb; ++i) a += log(bsum[i]);
        out_rz[0] = (float)(a / nb);
    }
}

// parallel per-expert scan over chunks
__global__ __launch_bounds__(1024)
void chunk_scan(const int* __restrict__ cnt2, const int* __restrict__ estart,
                int nchunks, int* __restrict__ cbase)
{
    __shared__ int sc[1024];
    const int e = blockIdx.x;    // 64 blocks
    const int t = threadIdx.x;   // 1024
    const int v = (t < nchunks) ? cnt2[(size_t)e * nchunks + t] : 0;
    sc[t] = v;
    __syncthreads();
#pragma unroll
    for (int off = 1; off < 1024; off <<= 1) {
        const int add = (t >= off) ? sc[t - off] : 0;
        __syncthreads();
        sc[t] += add;
        __syncthreads();
    }
    if (t < nchunks)
        cbase[(size_t)t * 64 + e] = estart[e] + sc[t] - v;   // exclusive
}

// stable scatter per 64-slot chunk
__global__ void scatter(const int* __restrict__ sel, const float* __restrict__ ts,
                        const int* __restrict__ cbase,
                        float* __restrict__ out_sc, float* __restrict__ out_idx)
{
    __shared__ int shx[64];
    const int lane = threadIdx.x;   // 64
    const int c = blockIdx.x;
    const int idx = c * 64 + lane;
    const int ex = sel[idx];
    shx[lane] = ex;
    __syncthreads();
    int pre = 0;
#pragma unroll
    for (int j = 0; j < 64; ++j) pre += (int)((j < lane) && (shx[j] == ex));
    const int pos = cbase[c * 64 + ex] + pre;
    out_sc[pos]  = ts[idx];
    out_idx[pos] = (float)(idx >> 1);
}

extern "C" void kernel_launch(void* const* d_in, const int* in_sizes, int n_in,
                              void* d_out, int out_size, void* d_ws, size_t ws_size,
                              hipStream_t stream)
{
    const float* x = (const float*)d_in[0];
    const float* W = (const float*)d_in[1];
    const float* b = (const float*)d_in[2];
    const int* bs_p = (const int*)d_in[3];
    const int* sl_p = (const int*)d_in[4];

    const int E   = in_sizes[2];           // 64
    const int dim = in_sizes[1] / E;       // 2048
    const int N   = in_sizes[0] / dim;     // 16384
    const int total = N * 2;               // slots
    const int nchunks = total / 64;        // 512

    char* ws = (char*)d_ws;
    size_t off = 0;
    int*    hist     = (int*)(ws + off); off += 256;
    double* bsum     = (double*)(ws + off); off += 512;
    int*    nflags   = (int*)(ws + off); off += 256;
    int*    estart   = (int*)(ws + off); off += 256;
    float*  ts       = (float*)(ws + off); off += (size_t)total * 4;
    int*    sel      = (int*)(ws + off); off += (size_t)total * 4;
    int*    flaglist = (int*)(ws + off); off += (size_t)N * 4;
    float*  rzrow    = (float*)(ws + off); off += (size_t)N * 4;
    int*    cnt2     = (int*)(ws + off); off += (size_t)nchunks * 64 * 4;
    int*    cbase    = (int*)(ws + off); off += (size_t)nchunks * 64 * 4;
    float*  z        = (float*)(ws + off); off += (size_t)N * 64 * 4;

    // pick largest ksplit whose zpart fits the workspace
    int ksplit = 8;
    while (ksplit > 1 &&
           off + (size_t)ksplit * N * 64 * sizeof(float) > ws_size)
        ksplit >>= 1;
    float* zpart = (float*)(ws + off);

    float* out_sc  = (float*)d_out;
    float* out_idx = out_sc + total;
    float* out_cnt = out_idx + total;
    float* out_rz  = out_cnt + E;

    hipMemsetAsync(ws, 0, 1280, stream);

    const int rgs = N / 64;  // 256 row groups
    hipLaunchKernelGGL((gemm_rows<16>), dim3(rgs * ksplit), dim3(256), 0, stream,
                       x, W, dim, N, ksplit, rgs, zpart);
    hipLaunchKernelGGL(zred, dim3(N * 16 / 256), dim3(256), 0, stream,
                       zpart, b, N, ksplit, z);
    hipLaunchKernelGGL(epilogue, dim3(N / 256), dim3(256), 0, stream,
                       z, N, ts, sel, rzrow, nflags, flaglist);
    hipLaunchKernelGGL(fixup, dim3(512), dim3(1024), 0, stream,
                       x, W, b, dim, nflags, flaglist, ts, sel);
    hipLaunchKernelGGL(hist_chunks, dim3(nchunks), dim3(64), 0, stream,
                       sel, nchunks, hist, cnt2);
    hipLaunchKernelGGL(rz_batch, dim3(64), dim3(256), 0, stream,
                       rzrow, bs_p, sl_p, bsum);
    hipLaunchKernelGGL(combine, dim3(1), dim3(64), 0, stream,
                       hist, estart, bsum, bs_p, out_cnt, out_rz);
    hipLaunchKernelGGL(chunk_scan, dim3(64), dim3(1024), 0, stream,
                       cnt2, estart, nchunks, cbase);
    hipLaunchKernelGGL(scatter, dim3(nchunks), dim3(64), 0, stream,
                       sel, ts, cbase, out_sc, out_idx);
}